// Round 1
// 255.057 us; speedup vs baseline: 1.1020x; 1.1020x over previous
//
#include <hip/hip_runtime.h>

// B=16, C=256, H=W=64 -> N=4096, NH=4, HD=64, G=32 (8 ch/group), K=256
// ALL inputs and d_out are FP32. Internal: bf16 operands + fp32 acc.
// qkv rows: o in [0,768): q=[0,256), k=[256,512), v=[512,768)
// Workspace:
//   qkv  : (o, b*N + n) 768 x 65536 bf16 = 100,663,296 B at +0
//   ctx  : (b*4+h,e,d)  64 x 64 x 64 f32 =   1,048,576 B at +100663296
//   scsh : (b,c) float2                  =      32,768 B at +101711872
//   qst  : (o,b) float2 256x16           =      32,768 B at +101744640
//   wbf  : qkv_w bf16 768x256            =     393,216 B at +101777408
//   W2   : (b,o,c') 16x256x256 bf16 (2MB) reuses dead k-rows (+33554432)
// Pipeline: gn_stats(+wcast fused) -> gemm1(GN fused, full-K B^T resident,
//           512 blk x 6 m-tiles) -> qstats -> ctx_mfma(k-softmax fused)
//           -> w2 -> gemm2(q-softmax fused)

typedef __bf16 bf16x8 __attribute__((ext_vector_type(8)));
typedef __bf16 bf16x4 __attribute__((ext_vector_type(4)));
typedef __bf16 bf16x2 __attribute__((ext_vector_type(2)));
typedef float  f32x4  __attribute__((ext_vector_type(4)));

__device__ __forceinline__ float wave_red_sum(float v) {
#pragma unroll
    for (int off = 32; off > 0; off >>= 1) v += __shfl_xor(v, off, 64);
    return v;
}
__device__ __forceinline__ float wave_red_max(float v) {
#pragma unroll
    for (int off = 32; off > 0; off >>= 1) v = fmaxf(v, __shfl_xor(v, off, 64));
    return v;
}

// ---------------------------------------------------------------------------
// GroupNorm stats -> per-channel (sc, sh); grid 512 = (b16 x g32), block 256
// wcast (qkv_w fp32 -> bf16, 196608 elems) folded in: 2 elems/thread.
// ---------------------------------------------------------------------------
__global__ __launch_bounds__(256)
void gn_stats_kernel(const float* __restrict__ x, const float* __restrict__ gw,
                     const float* __restrict__ gb, const float* __restrict__ qw,
                     float2* __restrict__ scsh, __bf16* __restrict__ wb)
{
    const int blk = blockIdx.x;
    const int b = blk >> 5, g = blk & 31;
    const int tid = threadIdx.x;
    const int lane = tid & 63, wid = tid >> 6;
    const size_t xbase = ((size_t)(b * 256 + g * 8)) * 4096;

    // fused wcast: 512 blk * 256 thr * 2 = 262144 slots >= 196608 elems
    {
        const int ci = (blk * 256 + tid) * 2;
        if (ci < 196608) {
            const float2 f = *(const float2*)(qw + ci);
            bf16x2 t; t[0] = (__bf16)f.x; t[1] = (__bf16)f.y;
            *(bf16x2*)(wb + ci) = t;
        }
    }

    float s1 = 0.f, s2 = 0.f;
#pragma unroll
    for (int it = 0; it < 32; it++) {
        const int idx = (it * 256 + tid) * 4;
        const float4 v4 = *(const float4*)(x + xbase + idx);
        s1 += v4.x + v4.y + v4.z + v4.w;
        s2 += v4.x * v4.x + v4.y * v4.y + v4.z * v4.z + v4.w * v4.w;
    }
    __shared__ float red[8];
    float s1w = wave_red_sum(s1);
    float s2w = wave_red_sum(s2);
    if (lane == 0) { red[wid] = s1w; red[4 + wid] = s2w; }
    __syncthreads();
    const float mean = (red[0] + red[1] + red[2] + red[3]) * (1.0f / 32768.0f);
    const float ms   = (red[4] + red[5] + red[6] + red[7]) * (1.0f / 32768.0f);
    const float inv  = rsqrtf(fmaxf(ms - mean * mean, 0.f) + 1e-5f);

    if (tid < 8) {
        const int c = g * 8 + tid;
        const float sc = gw[c] * inv;
        const float sh = gb[c] - mean * sc;
        scsh[b * 256 + c] = make_float2(sc, sh);
    }
}

// ---------------------------------------------------------------------------
// gemm1: qkv[o][bn] = sum_c wbf[o][c] * gn(x)[c][bn] + bias.
// v2: full-K B^T resident in LDS (staged ONCE, GN fused), loop 6 m-tiles.
// grid 512 n-tiles (=2 blocks/CU, all resident); block 256 (4 waves).
// LDS ~80 KB (gemm2-proven footprint). x is read exactly once from HBM.
// A (wbf) streamed per kt-step with register prefetch overlapping MFMA.
// ---------------------------------------------------------------------------
__global__ __launch_bounds__(256)
void gemm1_kernel(const __bf16* __restrict__ wbf,
                  const float* __restrict__ x,
                  const float* __restrict__ bias,
                  const float2* __restrict__ scsh,
                  __bf16* __restrict__ qkv)
{
    __shared__ __align__(16) __bf16 lds_bt[128 * 264];  // B^T: [n][c], 67584 B
    __shared__ __align__(16) __bf16 lds_a[128 * 40];    // A:   [m][k], 10240 B
    __shared__ float2 lscsh[256];

    const int tid  = threadIdx.x;
    const int lane = tid & 63;
    const int wid  = tid >> 6;
    const int quad = lane >> 4;
    const int tcol = lane & 15;
    const int wm   = (wid & 1) * 64;
    const int wn   = (wid >> 1) * 64;
    const int n0   = blockIdx.x * 128;
    const int b    = n0 >> 12;
    const int nn   = n0 & 4095;

    lscsh[tid] = scsh[b * 256 + tid];
    __syncthreads();

    // stage B^T once: [n 128][c 256] chunk-swizzled, GroupNorm fused
    const int sn    = tid & 127;
    const int chalf = tid >> 7;
    const int swz   = (sn >> 3) & 3;
    const float* xs = x + (size_t)b * 1048576 + nn + sn;
#pragma unroll
    for (int iter = 0; iter < 8; iter++) {
        const int cbase = iter * 32 + chalf * 16;
        bf16x8 o0, o1;
#pragma unroll
        for (int j = 0; j < 16; j++) {
            const int c = cbase + j;
            const float2 ss = lscsh[c];
            const float f = xs[(size_t)c * 4096];
            const __bf16 v = (__bf16)(f * ss.x + ss.y);
            if (j < 8) o0[j] = v; else o1[j - 8] = v;
        }
        const int chunk = iter * 2 + chalf;
        const int chSw  = chunk ^ swz;
        __bf16* dst = &lds_bt[sn * 264 + chSw * 16];
        *(bf16x8*)dst       = o0;
        *(bf16x8*)(dst + 8) = o1;
    }

    const int arow = tid >> 1, k16 = (tid & 1) * 16;
    const __bf16* asrc0 = wbf + (size_t)arow * 256 + k16;

    for (int mt = 0; mt < 6; mt++) {
        const int m0 = mt * 128;
        f32x4 acc[4][4];
#pragma unroll
        for (int i = 0; i < 4; i++)
#pragma unroll
            for (int j = 0; j < 4; j++) acc[i][j] = {0.f, 0.f, 0.f, 0.f};

        const __bf16* asrc = asrc0 + (size_t)m0 * 256;
        bf16x8 a0 = *(const bf16x8*)(asrc);
        bf16x8 a1 = *(const bf16x8*)(asrc + 8);

        for (int kt = 0; kt < 256; kt += 32) {
            __syncthreads();
            *(bf16x8*)&lds_a[arow * 40 + k16]     = a0;
            *(bf16x8*)&lds_a[arow * 40 + k16 + 8] = a1;
            if (kt < 224) {   // prefetch next A tile; overlaps with MFMA below
                const __bf16* an = asrc + kt + 32;
                a0 = *(const bf16x8*)(an);
                a1 = *(const bf16x8*)(an + 8);
            }
            __syncthreads();

            bf16x8 af[4];
#pragma unroll
            for (int mi = 0; mi < 4; mi++)
                af[mi] = *(const bf16x8*)&lds_a[(wm + mi * 16 + tcol) * 40 + quad * 8];
            bf16x8 bfr[4];
#pragma unroll
            for (int ni = 0; ni < 4; ni++) {
                const int n = wn + ni * 16 + tcol;
                const int k = kt + quad * 8;
                const int chSw2 = (k >> 4) ^ ((n >> 3) & 3);
                bfr[ni] = *(const bf16x8*)&lds_bt[n * 264 + chSw2 * 16 + (k & 15)];
            }
#pragma unroll
            for (int mi = 0; mi < 4; mi++)
#pragma unroll
                for (int ni = 0; ni < 4; ni++)
                    acc[mi][ni] = __builtin_amdgcn_mfma_f32_16x16x32_bf16(
                        af[mi], bfr[ni], acc[mi][ni], 0, 0, 0);
        }

        // epilogue: C/D layout col = lane&15 (N), row = quad*4 + r (M)
#pragma unroll
        for (int mi = 0; mi < 4; mi++) {
#pragma unroll
            for (int r = 0; r < 4; r++) {
                const int grow = m0 + wm + mi * 16 + quad * 4 + r;
                const float bv = bias[grow];
#pragma unroll
                for (int ni = 0; ni < 4; ni++) {
                    const int gcol = n0 + wn + ni * 16 + tcol;
                    qkv[(size_t)grow * 65536 + gcol] = (__bf16)(acc[mi][ni][r] + bv);
                }
            }
        }
    }
}

// ---------------------------------------------------------------------------
// qstats: per (o,b) row of q: (max, 1/sum(exp)) -> qst[o*16+b]
// grid 4096 = (o 256) x (b 16); block 256
// ---------------------------------------------------------------------------
__global__ __launch_bounds__(256)
void qstats_kernel(const __bf16* __restrict__ qkv, float2* __restrict__ qst)
{
    const int o = blockIdx.x >> 4;
    const int b = blockIdx.x & 15;
    const int tid = threadIdx.x;
    const int lane = tid & 63, wid = tid >> 6;
    const size_t base = (size_t)o * 65536 + (size_t)b * 4096;

    float v[16];
    float m = -INFINITY;
#pragma unroll
    for (int s = 0; s < 16; s++) {
        v[s] = (float)qkv[base + s * 256 + tid];
        m = fmaxf(m, v[s]);
    }
    __shared__ float red[4];
    float wmx = wave_red_max(m);
    if (lane == 0) red[wid] = wmx;
    __syncthreads();
    m = fmaxf(fmaxf(red[0], red[1]), fmaxf(red[2], red[3]));
    __syncthreads();
    float sum = 0.f;
#pragma unroll
    for (int s = 0; s < 16; s++) sum += __expf(v[s] - m);
    float wsm = wave_red_sum(sum);
    if (lane == 0) red[wid] = wsm;
    __syncthreads();
    if (tid == 0)
        qst[o * 16 + b] = make_float2(m, 1.0f / (red[0] + red[1] + red[2] + red[3]));
}

// ---------------------------------------------------------------------------
// ctx[bh][e][d] = sum_n v[e][n] * softmax_d(k)[d][n] via MFMA.
// grid 512 = (bh 64) x (kc 8); block 256 (4 waves, each owns a 32x32 quadrant)
// ---------------------------------------------------------------------------
__global__ __launch_bounds__(256)
void ctx_mfma_kernel(const __bf16* __restrict__ qkv, float* __restrict__ ctx)
{
    const int bh = blockIdx.x >> 3, kc = blockIdx.x & 7;
    const int b = bh >> 2, hh = bh & 3;
    __shared__ __align__(16) __bf16 lk[64 * 72], lv[64 * 72];
    __shared__ float smax[4][64], ssum[4][64];
    const int tid = threadIdx.x;
    const int lane = tid & 63, wid = tid >> 6;
    const int quad = lane >> 4, tcol = lane & 15;
    const int eh = (wid & 1) * 32, dh = (wid >> 1) * 32;
    const int col = tid & 63, dq = tid >> 6;
    const int sd = tid >> 2, snn = (tid & 3) * 16;

    f32x4 acc[2][2];
#pragma unroll
    for (int i = 0; i < 2; i++)
#pragma unroll
        for (int j = 0; j < 2; j++) acc[i][j] = {0.f, 0.f, 0.f, 0.f};

    const size_t kbase = (size_t)(256 + hh * 64) * 65536 + (size_t)b * 4096 + kc * 512;
    const size_t vbase = (size_t)(512 + hh * 64) * 65536 + (size_t)b * 4096 + kc * 512;

    for (int nc = 0; nc < 512; nc += 64) {
        __syncthreads();
        {   // stage k,v tiles [64 ch][64 n], row stride 72
            const __bf16* ks = qkv + kbase + (size_t)sd * 65536 + nc + snn;
            *(bf16x8*)&lk[sd * 72 + snn]     = *(const bf16x8*)ks;
            *(bf16x8*)&lk[sd * 72 + snn + 8] = *(const bf16x8*)(ks + 8);
            const __bf16* vs = qkv + vbase + (size_t)sd * 65536 + nc + snn;
            *(bf16x8*)&lv[sd * 72 + snn]     = *(const bf16x8*)vs;
            *(bf16x8*)&lv[sd * 72 + snn + 8] = *(const bf16x8*)(vs + 8);
        }
        __syncthreads();

        // fused k-softmax over d (full d=64 in tile per column)
        float kvv[16];
        float pm = -INFINITY;
#pragma unroll
        for (int i = 0; i < 16; i++) {
            kvv[i] = (float)lk[(dq * 16 + i) * 72 + col];
            pm = fmaxf(pm, kvv[i]);
        }
        smax[dq][col] = pm;
        __syncthreads();
        const float m = fmaxf(fmaxf(smax[0][col], smax[1][col]),
                              fmaxf(smax[2][col], smax[3][col]));
        float ps = 0.f;
#pragma unroll
        for (int i = 0; i < 16; i++) { kvv[i] = __expf(kvv[i] - m); ps += kvv[i]; }
        ssum[dq][col] = ps;
        __syncthreads();
        const float inv = 1.0f / (ssum[0][col] + ssum[1][col] + ssum[2][col] + ssum[3][col]);
#pragma unroll
        for (int i = 0; i < 16; i++)
            lk[(dq * 16 + i) * 72 + col] = (__bf16)(kvv[i] * inv);
        __syncthreads();

        // MFMA: D[e][d] += sum_n v[e][n] * k_sm[d][n]
#pragma unroll
        for (int k2 = 0; k2 < 64; k2 += 32) {
            bf16x8 af[2], bfr[2];
#pragma unroll
            for (int mi = 0; mi < 2; mi++)
                af[mi] = *(const bf16x8*)&lv[(eh + mi * 16 + tcol) * 72 + k2 + quad * 8];
#pragma unroll
            for (int ni = 0; ni < 2; ni++)
                bfr[ni] = *(const bf16x8*)&lk[(dh + ni * 16 + tcol) * 72 + k2 + quad * 8];
#pragma unroll
            for (int mi = 0; mi < 2; mi++)
#pragma unroll
                for (int ni = 0; ni < 2; ni++)
                    acc[mi][ni] = __builtin_amdgcn_mfma_f32_16x16x32_bf16(
                        af[mi], bfr[ni], acc[mi][ni], 0, 0, 0);
        }
    }
    float* cb = ctx + (size_t)bh * 4096;
#pragma unroll
    for (int mi = 0; mi < 2; mi++)
#pragma unroll
        for (int ni = 0; ni < 2; ni++)
#pragma unroll
            for (int r = 0; r < 4; r++) {
                const int e = eh + mi * 16 + quad * 4 + r;
                const int d = dh + ni * 16 + tcol;
                atomicAdd(&cb[e * 64 + d], acc[mi][ni][r]);
            }
}

// ---------------------------------------------------------------------------
// W2[b][o][h*64+d] = sum_e out_w[o][h*64+e] * ctx[bh][e][d]   (bf16 out)
// grid 64 = (b 16) x (h 4); block 256 (one thread per o)
// ---------------------------------------------------------------------------
__global__ __launch_bounds__(256)
void w2_kernel(const float* __restrict__ ctx, const float* __restrict__ out_w,
               __bf16* __restrict__ w2)
{
    const int bh = blockIdx.x;
    const int b = bh >> 2, hh = bh & 3;
    const int tid = threadIdx.x;

    __shared__ __align__(16) float lctx[4096];
    const float* csrc = ctx + (size_t)bh * 4096;
#pragma unroll
    for (int i = 0; i < 4; i++)
        ((float4*)lctx)[tid + i * 256] = ((const float4*)csrc)[tid + i * 256];
    __syncthreads();

    float acc[64];
#pragma unroll
    for (int d = 0; d < 64; d++) acc[d] = 0.f;

    const float* wrow = out_w + (size_t)tid * 256 + hh * 64;
    for (int e = 0; e < 64; e++) {
        const float w = wrow[e];
#pragma unroll
        for (int d4 = 0; d4 < 64; d4 += 4) {
            const float4 c4 = *(const float4*)&lctx[e * 64 + d4];
            acc[d4 + 0] += w * c4.x;
            acc[d4 + 1] += w * c4.y;
            acc[d4 + 2] += w * c4.z;
            acc[d4 + 3] += w * c4.w;
        }
    }
    __bf16* dst = w2 + (size_t)b * 65536 + (size_t)tid * 256 + hh * 64;
#pragma unroll
    for (int d4 = 0; d4 < 64; d4 += 4) {
        bf16x4 t;
        t[0] = (__bf16)acc[d4 + 0]; t[1] = (__bf16)acc[d4 + 1];
        t[2] = (__bf16)acc[d4 + 2]; t[3] = (__bf16)acc[d4 + 3];
        *(bf16x4*)(dst + d4) = t;
    }
}

// ---------------------------------------------------------------------------
// gemm2: out[b][o][n] = sum_c W2[b][o][c] * softmax_n(q)[c][bn] + out_b + x.
// Full-K B^T in LDS, MT=2; q-softmax fused into B^T staging using qstats.
// grid 512 n-tiles; block 256.
// ---------------------------------------------------------------------------
__global__ __launch_bounds__(256)
void gemm2_kernel(const __bf16* __restrict__ w2,
                  const __bf16* __restrict__ qkv,
                  const float2* __restrict__ qst,
                  const float* __restrict__ bias,
                  const float* __restrict__ xres,
                  float* __restrict__ out)
{
    __shared__ __align__(16) __bf16 lds_bt[128 * 264];  // B^T: [n][k], 67584 B
    __shared__ __align__(16) __bf16 lds_a[128 * 40];    // A:   [m][k], 10240 B
    __shared__ float2 lqst[256];

    const int tid  = threadIdx.x;
    const int lane = tid & 63;
    const int wid  = tid >> 6;
    const int quad = lane >> 4;
    const int tcol = lane & 15;
    const int wm   = (wid & 1) * 64;
    const int wn   = (wid >> 1) * 64;
    const int n0   = blockIdx.x * 128;
    const int b    = n0 >> 12;

    lqst[tid] = qst[tid * 16 + b];
    __syncthreads();

    const int sn    = tid & 127;
    const int chalf = tid >> 7;
    const int swz   = (sn >> 3) & 3;
#pragma unroll
    for (int iter = 0; iter < 8; iter++) {
        const int cbase = iter * 32 + chalf * 16;
        bf16x8 o0, o1;
        const __bf16* qs = qkv + n0 + sn;
#pragma unroll
        for (int j = 0; j < 16; j++) {
            const int c = cbase + j;
            const float2 qq = lqst[c];
            const float f = (float)qs[(size_t)c * 65536];
            const __bf16 v = (__bf16)(__expf(f - qq.x) * qq.y);
            if (j < 8) o0[j] = v; else o1[j - 8] = v;
        }
        const int chunk = iter * 2 + chalf;
        const int chSw  = chunk ^ swz;
        __bf16* dst = &lds_bt[sn * 264 + chSw * 16];
        *(bf16x8*)dst       = o0;
        *(bf16x8*)(dst + 8) = o1;
    }

    const int arow = tid >> 1, k16 = (tid & 1) * 16;

    for (int mt = 0; mt < 2; mt++) {
        const int m0 = mt * 128;
        f32x4 acc[4][4];
#pragma unroll
        for (int i = 0; i < 4; i++)
#pragma unroll
            for (int j = 0; j < 4; j++) acc[i][j] = {0.f, 0.f, 0.f, 0.f};

        for (int kt = 0; kt < 256; kt += 32) {
            __syncthreads();
            {   // stage A tile 128x32 from W2[b] (bf16)
                const __bf16* src = w2 + (size_t)b * 65536
                                  + (size_t)(m0 + arow) * 256 + kt + k16;
                const bf16x8 o0 = *(const bf16x8*)(src);
                const bf16x8 o1 = *(const bf16x8*)(src + 8);
                *(bf16x8*)&lds_a[arow * 40 + k16]     = o0;
                *(bf16x8*)&lds_a[arow * 40 + k16 + 8] = o1;
            }
            __syncthreads();

            bf16x8 af[4];
#pragma unroll
            for (int mi = 0; mi < 4; mi++)
                af[mi] = *(const bf16x8*)&lds_a[(wm + mi * 16 + tcol) * 40 + quad * 8];
            bf16x8 bfr[4];
#pragma unroll
            for (int ni = 0; ni < 4; ni++) {
                const int n = wn + ni * 16 + tcol;
                const int k = kt + quad * 8;
                const int chSw = (k >> 4) ^ ((n >> 3) & 3);
                bfr[ni] = *(const bf16x8*)&lds_bt[n * 264 + chSw * 16 + (k & 15)];
            }
#pragma unroll
            for (int mi = 0; mi < 4; mi++)
#pragma unroll
                for (int ni = 0; ni < 4; ni++)
                    acc[mi][ni] = __builtin_amdgcn_mfma_f32_16x16x32_bf16(
                        af[mi], bfr[ni], acc[mi][ni], 0, 0, 0);
        }

#pragma unroll
        for (int mi = 0; mi < 4; mi++) {
#pragma unroll
            for (int r = 0; r < 4; r++) {
                const int grow = m0 + wm + mi * 16 + quad * 4 + r;
                const float bv = bias[grow];
#pragma unroll
                for (int ni = 0; ni < 4; ni++) {
                    const int gcol = n0 + wn + ni * 16 + tcol;
                    const int n = gcol & 4095;
                    const size_t oidx = ((size_t)(b * 256 + grow)) * 4096 + n;
                    out[oidx] = acc[mi][ni][r] + bv + xres[oidx];
                }
            }
        }
    }
}

// ---------------------------------------------------------------------------
extern "C" void kernel_launch(void* const* d_in, const int* in_sizes, int n_in,
                              void* d_out, int out_size, void* d_ws, size_t ws_size,
                              hipStream_t stream)
{
    const float* x     = (const float*)d_in[0];
    const float* gn_w  = (const float*)d_in[1];
    const float* gn_b  = (const float*)d_in[2];
    const float* qkv_w = (const float*)d_in[3];
    const float* qkv_b = (const float*)d_in[4];
    const float* out_w = (const float*)d_in[5];
    const float* out_b = (const float*)d_in[6];
    float* out = (float*)d_out;

    char* ws = (char*)d_ws;
    __bf16* qkv  = (__bf16*)ws;                                   // 100,663,296 B
    float*  ctx  = (float*)(ws + (size_t)100663296);              //   1,048,576 B
    float2* scsh = (float2*)(ws + (size_t)101711872);             //      32,768 B
    float2* qst  = (float2*)(ws + (size_t)101744640);             //      32,768 B
    __bf16* wbf  = (__bf16*)(ws + (size_t)101777408);             //     393,216 B
    __bf16* w2   = qkv + (size_t)256 * 65536;                     // dead k rows

    hipMemsetAsync(ctx, 0, 262144 * sizeof(float), stream);
    gn_stats_kernel<<<512, 256, 0, stream>>>(x, gn_w, gn_b, qkv_w, scsh, wbf);
    gemm1_kernel<<<512, 256, 0, stream>>>(wbf, x, qkv_b, scsh, qkv);
    qstats_kernel<<<4096, 256, 0, stream>>>(qkv, qst);
    ctx_mfma_kernel<<<512, 256, 0, stream>>>(qkv, ctx);
    w2_kernel<<<64, 256, 0, stream>>>(ctx, out_w, w2);
    gemm2_kernel<<<512, 256, 0, stream>>>(w2, qkv, qst, out_b, x, out);
}